// Round 5
// baseline (2048.714 us; speedup 1.0000x reference)
//
#include <hip/hip_runtime.h>
#include <hip/hip_bf16.h>

typedef unsigned short u16;
typedef unsigned int u32;

#define DIM 128

__device__ __forceinline__ float bf2f(u16 v) { return __uint_as_float(((u32)v) << 16); }
__device__ __forceinline__ u16 f2bf(float x) {
  if (!(x == x)) x = 0.f;                       // NaN-proof
  if (x >  3.0e38f) x =  3.0e38f;               // Inf-proof
  if (x < -3.0e38f) x = -3.0e38f;
  u32 u = __float_as_uint(x);
  return (u16)((u + 0x7fffu + ((u >> 16) & 1u)) >> 16);  // RNE
}
__device__ __forceinline__ float lrelu(float x) { return x > 0.f ? x : 0.01f * x; }
__device__ __forceinline__ int iclamp(int v, int hi) { return v < 0 ? 0 : (v >= hi ? hi - 1 : v); }
__device__ __forceinline__ float sane(float x) { return (x == x) ? x : 0.f; }

__device__ __forceinline__ float wred_max(float v) {
  #pragma unroll
  for (int o = 32; o > 0; o >>= 1) v = fmaxf(v, __shfl_xor(v, o, 64));
  return v;
}

// ---------------- CSR build ----------------
__global__ void hist_k(const int* __restrict__ dst, int* __restrict__ cnt, int E, int N) {
  int e = blockIdx.x * blockDim.x + threadIdx.x;
  if (e < E) {
    int d = dst[e];
    if (d >= 0 && d < N) atomicAdd(&cnt[d], 1);
  }
}

__global__ __launch_bounds__(1024) void scan_k(const int* __restrict__ cnt,
                                               int* __restrict__ offs, int N) {
  __shared__ int sums[1024];
  int t = threadIdx.x;
  int chunk = (N + 1023) >> 10;
  int base = t * chunk;
  int s = 0;
  for (int i = 0; i < chunk; ++i) { int idx = base + i; if (idx < N) s += cnt[idx]; }
  sums[t] = s;
  __syncthreads();
  for (int off = 1; off < 1024; off <<= 1) {
    int v = (t >= off) ? sums[t - off] : 0;
    __syncthreads();
    sums[t] += v;
    __syncthreads();
  }
  int prefix = (t > 0) ? sums[t - 1] : 0;
  for (int i = 0; i < chunk; ++i) {
    int idx = base + i;
    if (idx < N) { offs[idx] = prefix; prefix += cnt[idx]; }
  }
  if (t == 1023) offs[N] = sums[1023];
}

__global__ void scatter_k(const int* __restrict__ dst, const int* __restrict__ offs,
                          int* __restrict__ cursor, int* __restrict__ eid, int E, int N) {
  int e = blockIdx.x * blockDim.x + threadIdx.x;
  if (e < E) {
    int d = dst[e];
    if (d >= 0 && d < N) {
      int pos = offs[d] + atomicAdd(&cursor[d], 1);
      if (pos >= 0 && pos < E) eid[pos] = e;
    }
  }
}

// ---------------- weight prep (f32) ----------------
// Wc[o][k] = sum_i W1[o][half+i] * Wmod[i][k]
__global__ void prep_wc(const float* __restrict__ W1, int half,
                        const float* __restrict__ Wmod, int Kmod,
                        float* __restrict__ out) {
  int k = blockIdx.x * blockDim.x + threadIdx.x;
  int o = blockIdx.y;
  if (k >= Kmod) return;
  float acc = 0.f;
  for (int i = 0; i < 128; ++i)
    acc += W1[o * 384 + half + i] * Wmod[i * Kmod + k];
  out[o * Kmod + k] = acc;
}

// split structural W1 into dst/src halves (f32)
__global__ void copy_w1(const float* __restrict__ W1,
                        float* __restrict__ WcD, float* __restrict__ WcS) {
  int k = threadIdx.x;
  int o = blockIdx.x;
  WcD[o * 128 + k] = W1[o * 384 + k];
  WcS[o * 128 + k] = W1[o * 384 + 128 + k];
}

// Pr[r][o] = W1c[o]·rel[r] + b1[o] + (W1a[o]+W1b[o])·bmod; qr[r] = Pr_row(f32)·w2
// one block per relation r, 128 threads (o = output dim)
__global__ __launch_bounds__(128) void prep_pr_q(
    const float* __restrict__ rel, const float* __restrict__ W1,
    const float* __restrict__ b1, const float* __restrict__ bmod,
    const float* __restrict__ w2,
    u16* __restrict__ Pr, float* __restrict__ qr, int NR) {
  __shared__ float red[128];
  int r = blockIdx.x;
  if (r >= NR) return;
  int o = threadIdx.x;
  float acc = b1[o];
  for (int i = 0; i < 128; ++i)
    acc += W1[o * 384 + 256 + i] * rel[r * 128 + i];
  if (bmod != nullptr) {
    for (int i = 0; i < 128; ++i)
      acc += (W1[o * 384 + i] + W1[o * 384 + 128 + i]) * bmod[i];
  }
  Pr[(size_t)r * 128 + o] = f2bf(acc);
  red[o] = acc * w2[o];
  __syncthreads();
  for (int s = 64; s > 0; s >>= 1) {
    if (o < s) red[o] += red[o + s];
    __syncthreads();
  }
  if (o == 0) qr[r] = sane(red[0]);
}

// ---------------- GEMM + fused q: P[M,128](bf16) = A[M,K] @ B[128,K]^T;
// q[n] = (A@B^T)[n,:] (f32) · w2.  One block per row n, 128 threads (o = col).
__global__ __launch_bounds__(128) void gemm_q(const float* __restrict__ A, int lda,
                                              const float* __restrict__ B,
                                              const float* __restrict__ w2,
                                              u16* __restrict__ P, float* __restrict__ q,
                                              int M, int K) {
  __shared__ float As[768];
  __shared__ float red[128];
  int n = blockIdx.x;
  if (n >= M) return;
  int o = threadIdx.x;
  for (int k = o; k < K; k += 128) As[k] = A[(size_t)n * lda + k];
  __syncthreads();
  const float* Brow = B + (size_t)o * K;
  float acc = 0.f;
  for (int k = 0; k < K; ++k) acc += As[k] * Brow[k];
  P[(size_t)n * 128 + o] = f2bf(acc);
  red[o] = acc * w2[o];
  __syncthreads();
  for (int s = 64; s > 0; s >>= 1) {
    if (o < s) red[o] += red[o + s];
    __syncthreads();
  }
  if (o == 0) q[n] = sane(red[0]);
}

// ---------------- per-node softmax + aggregation for ONE modality → f32 out ----
// one wave per node; lane covers output dims (2*lane, 2*lane+1)
__global__ __launch_bounds__(256) void aggregate_m(
    const int* __restrict__ eid, const int* __restrict__ offs,
    const int* __restrict__ src, const int* __restrict__ etyp,
    const float* __restrict__ qd, const float* __restrict__ qs, const float* __restrict__ qr,
    const u16* __restrict__ Pd, const u16* __restrict__ Ps, const u16* __restrict__ Pr,
    const float* __restrict__ alphaP, const float* __restrict__ gammaP,
    int mIdx, int first,
    float* __restrict__ outp,
    int N, int NR, int E) {
  int n = blockIdx.x * 4 + (threadIdx.x >> 6);
  if (n >= N) return;
  int lane = threadIdx.x & 63;
  int eb = offs[n], ee = offs[n + 1];
  if (eb < 0) eb = 0;
  if (eb > E) eb = E;
  if (ee < eb) ee = eb;
  if (ee > E) ee = E;
  int En = ee - eb;

  float al = alphaP[0];
  if (!(al > 0.f && al < 1.f)) al = 0.1f;
  float ga = gammaP[0];
  if (!(ga > 0.f && ga < 1.f)) ga = 0.8f;
  float coef = (mIdx == 0) ? (1.f - al - ga) : (mIdx == 1 ? al : ga);

  float qdn = sane(qd[n]);

  // pass 1: segment max of on-the-fly logits
  float mx = -1e30f;
  for (int i = lane; i < En; i += 64) {
    int e = iclamp(eid[eb + i], E);
    int s = iclamp(src[e], N);
    int t = iclamp(etyp[e], NR);
    mx = fmaxf(mx, lrelu(qdn + sane(qs[s]) + sane(qr[t])));
  }
  mx = wred_max(mx);

  // pass 2 (fused): z and unnormalized accumulation; lane covers dims 2l,2l+1
  float z = 0.f, a0 = 0.f, a1 = 0.f;
  for (int c0 = 0; c0 < En; c0 += 64) {
    int cn = min(64, En - c0);
    float wraw = 0.f;
    int s = 0, t = 0;
    if (lane < cn) {
      int e = iclamp(eid[eb + c0 + lane], E);
      s = iclamp(src[e], N);
      t = iclamp(etyp[e], NR);
      float b = lrelu(qdn + sane(qs[s]) + sane(qr[t]));
      float arg = fmaxf(fminf(b - mx, 0.f), -80.f);
      wraw = __expf(arg);
    }
    z += wraw;
    for (int j = 0; j < cn; ++j) {
      float wj = __shfl(wraw, j, 64);
      int sj = __shfl(s, j, 64);
      int tj = __shfl(t, j, 64);
      u32 pu = *reinterpret_cast<const u32*>(Ps + (size_t)sj * 128 + 2 * lane);
      u32 ru = *reinterpret_cast<const u32*>(Pr + (size_t)tj * 128 + 2 * lane);
      float ps0 = __uint_as_float(pu << 16), ps1 = __uint_as_float(pu & 0xffff0000u);
      float pr0 = __uint_as_float(ru << 16), pr1 = __uint_as_float(ru & 0xffff0000u);
      a0 = fmaf(wj, sane(ps0) + sane(pr0), a0);
      a1 = fmaf(wj, sane(ps1) + sane(pr1), a1);
    }
  }
  #pragma unroll
  for (int o = 32; o > 0; o >>= 1) z += __shfl_xor(z, o, 64);

  float h0 = 0.f, h1 = 0.f;
  if (En > 0 && z > 0.f) {
    float rz = 1.f / z;
    u32 du = *reinterpret_cast<const u32*>(Pd + (size_t)n * 128 + 2 * lane);
    float pd0 = __uint_as_float(du << 16), pd1 = __uint_as_float(du & 0xffff0000u);
    h0 = lrelu(sane(pd0) + a0 * rz);
    h1 = lrelu(sane(pd1) + a1 * rz);
  }
  float c0v = sane(coef * h0);
  float c1v = sane(coef * h1);

  // f32 output, accumulate across modalities; m=0 overwrites (poison-safe)
  float* op = outp + (size_t)n * 128 + 2 * lane;
  if (first) {
    op[0] = c0v;
    op[1] = c1v;
  } else {
    op[0] = sane(op[0]) + c0v;
    op[1] = sane(op[1]) + c1v;
  }
}

extern "C" void kernel_launch(void* const* d_in, const int* in_sizes, int n_in,
                              void* d_out, int out_size, void* d_ws, size_t ws_size,
                              hipStream_t stream) {
  const int* ei        = (const int*)d_in[1];
  const int* et        = (const int*)d_in[2];
  const float* visual  = (const float*)d_in[3];
  const float* textual = (const float*)d_in[4];
  const float* semb    = (const float*)d_in[5];
  const float* relemb  = (const float*)d_in[6];
  const float* W1s = (const float*)d_in[7];
  const float* b1s = (const float*)d_in[8];
  const float* w2s = (const float*)d_in[9];
  const float* W1v = (const float*)d_in[10];
  const float* b1v = (const float*)d_in[11];
  const float* w2v = (const float*)d_in[12];
  const float* W1t = (const float*)d_in[13];
  const float* b1t = (const float*)d_in[14];
  const float* w2t = (const float*)d_in[15];
  const float* Wv  = (const float*)d_in[16];
  const float* bv  = (const float*)d_in[17];
  const float* Wt  = (const float*)d_in[18];
  const float* bt  = (const float*)d_in[19];
  const float* alphaP = (const float*)d_in[20];
  const float* gammaP = (const float*)d_in[21];
  float* outp = (float*)d_out;   // reference output dtype = float32

  const int E   = in_sizes[2];
  const int N   = in_sizes[5] / DIM;
  const int NR  = in_sizes[6] / DIM;
  const int VIS = in_sizes[3] / N;   // 512
  const int TXT = in_sizes[4] / N;   // 768
  const int KMAX = (TXT > VIS) ? TXT : VIS;

  // ---- workspace layout (metadata first), gated on ws_size ----
  size_t off = 0;
  auto take = [&](size_t bytes) -> size_t {
    size_t o = off;
    off = (off + bytes + 255) & ~(size_t)255;
    return o;
  };
  size_t o_cnt  = take((size_t)2 * N * 4);
  size_t o_offs = take((size_t)(N + 1) * 4);
  size_t o_eid  = take((size_t)E * 4);
  size_t o_qd   = take((size_t)N * 4);
  size_t o_qs   = take((size_t)N * 4);
  size_t o_qr   = take((size_t)NR * 4);
  size_t o_Pr   = take((size_t)NR * 128 * 2);
  size_t o_WcD  = take((size_t)128 * KMAX * 4);
  size_t o_WcS  = take((size_t)128 * KMAX * 4);
  size_t o_Pd   = take((size_t)N * 128 * 2);
  size_t o_Ps   = take((size_t)N * 128 * 2);
  size_t need   = off;   // ~7.44 MB (same footprint round 4 proved resident)

  if (ws_size < need) {
    hipMemsetAsync(d_out, 0, (size_t)out_size * 4, stream);  // finite diagnostic
    return;
  }

  char* w = (char*)d_ws;
  int* counts = (int*)(w + o_cnt);
  int* cursor = counts + N;
  int* offs   = (int*)(w + o_offs);
  int* eid    = (int*)(w + o_eid);
  float* qd   = (float*)(w + o_qd);
  float* qs   = (float*)(w + o_qs);
  float* qr   = (float*)(w + o_qr);
  u16* Pr     = (u16*)(w + o_Pr);
  float* WcD  = (float*)(w + o_WcD);
  float* WcS  = (float*)(w + o_WcS);
  u16* Pd     = (u16*)(w + o_Pd);
  u16* Ps     = (u16*)(w + o_Ps);

  const int* esrc = ei;
  const int* edst = ei + E;

  hipMemsetAsync(counts, 0, (size_t)2 * N * 4, stream);
  hipMemsetAsync(eid, 0, (size_t)E * 4, stream);

  int egrid = (E + 255) / 256;
  hist_k<<<egrid, 256, 0, stream>>>(edst, counts, E, N);
  scan_k<<<1, 1024, 0, stream>>>(counts, offs, N);
  scatter_k<<<egrid, 256, 0, stream>>>(edst, offs, cursor, eid, E, N);

  for (int m = 0; m < 3; ++m) {
    const float *W1, *b1, *w2, *Amod, *Wmod, *bmod;
    int K;
    if (m == 0)      { W1 = W1s; b1 = b1s; w2 = w2s; Amod = semb;    Wmod = nullptr; bmod = nullptr; K = DIM; }
    else if (m == 1) { W1 = W1v; b1 = b1v; w2 = w2v; Amod = visual;  Wmod = Wv;      bmod = bv;      K = VIS; }
    else             { W1 = W1t; b1 = b1t; w2 = w2t; Amod = textual; Wmod = Wt;      bmod = bt;      K = TXT; }

    if (m == 0) {
      copy_w1<<<128, 128, 0, stream>>>(W1, WcD, WcS);
    } else {
      prep_wc<<<dim3((K + 255) / 256, 128), 256, 0, stream>>>(W1, 0,   Wmod, K, WcD);
      prep_wc<<<dim3((K + 255) / 256, 128), 256, 0, stream>>>(W1, 128, Wmod, K, WcS);
    }
    prep_pr_q<<<NR, 128, 0, stream>>>(relemb, W1, b1, bmod, w2, Pr, qr, NR);

    gemm_q<<<N, 128, 0, stream>>>(Amod, K, WcD, w2, Pd, qd, N, K);
    gemm_q<<<N, 128, 0, stream>>>(Amod, K, WcS, w2, Ps, qs, N, K);

    aggregate_m<<<(N + 3) / 4, 256, 0, stream>>>(eid, offs, esrc, et,
                                                 qd, qs, qr, Pd, Ps, Pr,
                                                 alphaP, gammaP, m, (m == 0) ? 1 : 0,
                                                 outp, N, NR, E);
  }
}

// Round 6
// 435.219 us; speedup vs baseline: 4.7073x; 4.7073x over previous
//
#include <hip/hip_runtime.h>
#include <hip/hip_bf16.h>

typedef unsigned short u16;
typedef unsigned int u32;
typedef __bf16 bf16x8 __attribute__((ext_vector_type(8)));
typedef float f32x4 __attribute__((ext_vector_type(4)));

#define DIM 128

__device__ __forceinline__ float bf2f(u16 v) { return __uint_as_float(((u32)v) << 16); }
__device__ __forceinline__ u16 f2bf_rne(float x) {   // inputs known-finite
  u32 u = __float_as_uint(x);
  return (u16)((u + 0x7fffu + ((u >> 16) & 1u)) >> 16);
}
__device__ __forceinline__ u16 f2bf(float x) {       // guarded (output path)
  if (!(x == x)) x = 0.f;
  if (x >  3.0e38f) x =  3.0e38f;
  if (x < -3.0e38f) x = -3.0e38f;
  return f2bf_rne(x);
}
__device__ __forceinline__ float lrelu(float x) { return x > 0.f ? x : 0.01f * x; }
__device__ __forceinline__ int iclamp(int v, int hi) { return v < 0 ? 0 : (v >= hi ? hi - 1 : v); }
__device__ __forceinline__ float sane(float x) { return (x == x) ? x : 0.f; }

__device__ __forceinline__ float wred_max(float v) {
  #pragma unroll
  for (int o = 32; o > 0; o >>= 1) v = fmaxf(v, __shfl_xor(v, o, 64));
  return v;
}

// ---------------- CSR build ----------------
__global__ void hist_k(const int* __restrict__ dst, int* __restrict__ cnt, int E, int N) {
  int e = blockIdx.x * blockDim.x + threadIdx.x;
  if (e < E) {
    int d = dst[e];
    if (d >= 0 && d < N) atomicAdd(&cnt[d], 1);
  }
}

__global__ __launch_bounds__(1024) void scan_k(const int* __restrict__ cnt,
                                               int* __restrict__ offs, int N) {
  __shared__ int sums[1024];
  int t = threadIdx.x;
  int chunk = (N + 1023) >> 10;
  int base = t * chunk;
  int s = 0;
  for (int i = 0; i < chunk; ++i) { int idx = base + i; if (idx < N) s += cnt[idx]; }
  sums[t] = s;
  __syncthreads();
  for (int off = 1; off < 1024; off <<= 1) {
    int v = (t >= off) ? sums[t - off] : 0;
    __syncthreads();
    sums[t] += v;
    __syncthreads();
  }
  int prefix = (t > 0) ? sums[t - 1] : 0;
  for (int i = 0; i < chunk; ++i) {
    int idx = base + i;
    if (idx < N) { offs[idx] = prefix; prefix += cnt[idx]; }
  }
  if (t == 1023) offs[N] = sums[1023];
}

__global__ void scatter_k(const int* __restrict__ dst, const int* __restrict__ offs,
                          int* __restrict__ cursor, int* __restrict__ eid, int E, int N) {
  int e = blockIdx.x * blockDim.x + threadIdx.x;
  if (e < E) {
    int d = dst[e];
    if (d >= 0 && d < N) {
      int pos = offs[d] + atomicAdd(&cursor[d], 1);
      if (pos >= 0 && pos < E) eid[pos] = e;
    }
  }
}

// ---------------- weight prep → combined bf16 B[256][K] (rows 0-127 = D, 128-255 = S)
__global__ void prep_wc2(const float* __restrict__ W1, const float* __restrict__ Wmod,
                         int K, u16* __restrict__ out) {
  int k = blockIdx.x * blockDim.x + threadIdx.x;
  int o = blockIdx.y;                       // 0..255
  if (k >= K) return;
  int half = (o >= 128) ? 128 : 0;
  int oo = o & 127;
  float acc = 0.f;
  for (int i = 0; i < 128; ++i)
    acc += W1[oo * 384 + half + i] * Wmod[i * K + k];
  out[(size_t)o * K + k] = f2bf_rne(acc);
}

__global__ void copy_w1b(const float* __restrict__ W1, u16* __restrict__ out) {
  int k = threadIdx.x;                      // 128
  int o = blockIdx.x;                       // 256
  int half = (o >= 128) ? 128 : 0;
  int oo = o & 127;
  out[o * 128 + k] = f2bf_rne(W1[oo * 384 + half + k]);
}

// Pr[r][o] (bf16) + qr[r] (f32), one block per relation
__global__ __launch_bounds__(128) void prep_pr_q(
    const float* __restrict__ rel, const float* __restrict__ W1,
    const float* __restrict__ b1, const float* __restrict__ bmod,
    const float* __restrict__ w2,
    u16* __restrict__ Pr, float* __restrict__ qr, int NR) {
  __shared__ float red[128];
  int r = blockIdx.x;
  if (r >= NR) return;
  int o = threadIdx.x;
  float acc = b1[o];
  for (int i = 0; i < 128; ++i)
    acc += W1[o * 384 + 256 + i] * rel[r * 128 + i];
  if (bmod != nullptr) {
    for (int i = 0; i < 128; ++i)
      acc += (W1[o * 384 + i] + W1[o * 384 + 128 + i]) * bmod[i];
  }
  Pr[(size_t)r * 128 + o] = f2bf_rne(acc);
  red[o] = acc * w2[o];
  __syncthreads();
  for (int s = 64; s > 0; s >>= 1) {
    if (o < s) red[o] += red[o + s];
    __syncthreads();
  }
  if (o == 0) qr[r] = sane(red[0]);
}

// ---------------- MFMA GEMM: [Pd|Ps][M,128](bf16) = A[M,K](f32→bf16) @ B[256,K]^T
// also q{d,s}[n] = f32 row · w2 fused in the epilogue.
// block = 256 threads (4 waves), tile 64 rows × 256 cols, BK=32.
// C/D layout (verified): col = lane&15, row = (lane>>4)*4 + reg
__global__ __launch_bounds__(256) void gemm2_mfma(
    const float* __restrict__ A, const u16* __restrict__ Bbf,
    const float* __restrict__ w2,
    u16* __restrict__ Pd, u16* __restrict__ Ps,
    float* __restrict__ qd, float* __restrict__ qs,
    int M, int K) {
  __shared__ u16 Asb[64 * 32];    // 4 KB
  __shared__ u16 Bsb[256 * 32];   // 16 KB
  int tid = threadIdx.x;
  int lane = tid & 63, wv = tid >> 6;
  int quad = lane >> 4, l16 = lane & 15;
  int row0 = blockIdx.x * 64;

  f32x4 acc[16];
  #pragma unroll
  for (int t = 0; t < 16; ++t) acc[t] = (f32x4){0.f, 0.f, 0.f, 0.f};

  int arow = tid >> 2, ac0 = (tid & 3) * 8;
  int garow = row0 + arow;
  if (garow >= M) garow = M - 1;            // safe dup loads; stores guarded
  const float* Ab = A + (size_t)garow * K;

  for (int k0 = 0; k0 < K; k0 += 32) {
    __syncthreads();
    // stage A: 8 f32 per thread → bf16 → LDS (16B aligned)
    const float* Ag = Ab + k0 + ac0;
    float4 v0 = *reinterpret_cast<const float4*>(Ag);
    float4 v1 = *reinterpret_cast<const float4*>(Ag + 4);
    u32* al = reinterpret_cast<u32*>(&Asb[arow * 32 + ac0]);
    al[0] = (u32)f2bf_rne(v0.x) | ((u32)f2bf_rne(v0.y) << 16);
    al[1] = (u32)f2bf_rne(v0.z) | ((u32)f2bf_rne(v0.w) << 16);
    al[2] = (u32)f2bf_rne(v1.x) | ((u32)f2bf_rne(v1.y) << 16);
    al[3] = (u32)f2bf_rne(v1.z) | ((u32)f2bf_rne(v1.w) << 16);
    // stage B: thread tid copies row tid's 32 bf16 (64 B)
    const uint4* Bg = reinterpret_cast<const uint4*>(Bbf + (size_t)tid * K + k0);
    uint4* bl = reinterpret_cast<uint4*>(&Bsb[tid * 32]);
    bl[0] = Bg[0]; bl[1] = Bg[1]; bl[2] = Bg[2]; bl[3] = Bg[3];
    __syncthreads();

    bf16x8 a = *reinterpret_cast<const bf16x8*>(&Asb[(wv * 16 + l16) * 32 + quad * 8]);
    #pragma unroll
    for (int t = 0; t < 16; ++t) {
      bf16x8 b = *reinterpret_cast<const bf16x8*>(&Bsb[(t * 16 + l16) * 32 + quad * 8]);
      acc[t] = __builtin_amdgcn_mfma_f32_16x16x32_bf16(a, b, acc[t], 0, 0, 0);
    }
  }

  // epilogue: stores + fused q reduction
  float w2c[8];
  #pragma unroll
  for (int t = 0; t < 8; ++t) w2c[t] = w2[t * 16 + l16];

  #pragma unroll
  for (int r = 0; r < 4; ++r) {
    int rr = row0 + wv * 16 + quad * 4 + r;
    bool ok = rr < M;
    float qdp = 0.f, qsp = 0.f;
    #pragma unroll
    for (int t = 0; t < 8; ++t) {
      if (ok) {
        Pd[(size_t)rr * 128 + t * 16 + l16] = f2bf_rne(acc[t][r]);
        Ps[(size_t)rr * 128 + t * 16 + l16] = f2bf_rne(acc[t + 8][r]);
      }
      qdp += acc[t][r] * w2c[t];
      qsp += acc[t + 8][r] * w2c[t];
    }
    #pragma unroll
    for (int mk = 1; mk < 16; mk <<= 1) {
      qdp += __shfl_xor(qdp, mk, 64);
      qsp += __shfl_xor(qsp, mk, 64);
    }
    if (ok && l16 == 0) { qd[rr] = sane(qdp); qs[rr] = sane(qsp); }
  }
}

// ---------------- per-node softmax + aggregation for ONE modality → f32 out ----
__global__ __launch_bounds__(256) void aggregate_m(
    const int* __restrict__ eid, const int* __restrict__ offs,
    const int* __restrict__ src, const int* __restrict__ etyp,
    const float* __restrict__ qd, const float* __restrict__ qs, const float* __restrict__ qr,
    const u16* __restrict__ Pd, const u16* __restrict__ Ps, const u16* __restrict__ Pr,
    const float* __restrict__ alphaP, const float* __restrict__ gammaP,
    int mIdx, int first,
    float* __restrict__ outp,
    int N, int NR, int E) {
  int n = blockIdx.x * 4 + (threadIdx.x >> 6);
  if (n >= N) return;
  int lane = threadIdx.x & 63;
  int eb = offs[n], ee = offs[n + 1];
  if (eb < 0) eb = 0;
  if (eb > E) eb = E;
  if (ee < eb) ee = eb;
  if (ee > E) ee = E;
  int En = ee - eb;

  float al = alphaP[0];
  if (!(al > 0.f && al < 1.f)) al = 0.1f;
  float ga = gammaP[0];
  if (!(ga > 0.f && ga < 1.f)) ga = 0.8f;
  float coef = (mIdx == 0) ? (1.f - al - ga) : (mIdx == 1 ? al : ga);

  float qdn = sane(qd[n]);

  // pass 1: segment max
  float mx = -1e30f;
  for (int i = lane; i < En; i += 64) {
    int e = iclamp(eid[eb + i], E);
    int s = iclamp(src[e], N);
    int t = iclamp(etyp[e], NR);
    mx = fmaxf(mx, lrelu(qdn + sane(qs[s]) + sane(qr[t])));
  }
  mx = wred_max(mx);

  // pass 2 (fused): z and unnormalized accumulation; lane covers dims 2l,2l+1
  float z = 0.f, a0 = 0.f, a1 = 0.f;
  for (int c0 = 0; c0 < En; c0 += 64) {
    int cn = min(64, En - c0);
    float wraw = 0.f;
    int s = 0, t = 0;
    if (lane < cn) {
      int e = iclamp(eid[eb + c0 + lane], E);
      s = iclamp(src[e], N);
      t = iclamp(etyp[e], NR);
      float b = lrelu(qdn + sane(qs[s]) + sane(qr[t]));
      float arg = fmaxf(fminf(b - mx, 0.f), -80.f);
      wraw = __expf(arg);
    }
    z += wraw;
    for (int j = 0; j < cn; ++j) {
      float wj = __shfl(wraw, j, 64);
      int sj = __shfl(s, j, 64);
      int tj = __shfl(t, j, 64);
      u32 pu = *reinterpret_cast<const u32*>(Ps + (size_t)sj * 128 + 2 * lane);
      u32 ru = *reinterpret_cast<const u32*>(Pr + (size_t)tj * 128 + 2 * lane);
      float ps0 = __uint_as_float(pu << 16), ps1 = __uint_as_float(pu & 0xffff0000u);
      float pr0 = __uint_as_float(ru << 16), pr1 = __uint_as_float(ru & 0xffff0000u);
      a0 = fmaf(wj, sane(ps0) + sane(pr0), a0);
      a1 = fmaf(wj, sane(ps1) + sane(pr1), a1);
    }
  }
  #pragma unroll
  for (int o = 32; o > 0; o >>= 1) z += __shfl_xor(z, o, 64);

  float h0 = 0.f, h1 = 0.f;
  if (En > 0 && z > 0.f) {
    float rz = 1.f / z;
    u32 du = *reinterpret_cast<const u32*>(Pd + (size_t)n * 128 + 2 * lane);
    float pd0 = __uint_as_float(du << 16), pd1 = __uint_as_float(du & 0xffff0000u);
    h0 = lrelu(sane(pd0) + a0 * rz);
    h1 = lrelu(sane(pd1) + a1 * rz);
  }
  float c0v = sane(coef * h0);
  float c1v = sane(coef * h1);

  float* op = outp + (size_t)n * 128 + 2 * lane;
  if (first) {
    op[0] = c0v;
    op[1] = c1v;
  } else {
    op[0] = sane(op[0]) + c0v;
    op[1] = sane(op[1]) + c1v;
  }
}

extern "C" void kernel_launch(void* const* d_in, const int* in_sizes, int n_in,
                              void* d_out, int out_size, void* d_ws, size_t ws_size,
                              hipStream_t stream) {
  const int* ei        = (const int*)d_in[1];
  const int* et        = (const int*)d_in[2];
  const float* visual  = (const float*)d_in[3];
  const float* textual = (const float*)d_in[4];
  const float* semb    = (const float*)d_in[5];
  const float* relemb  = (const float*)d_in[6];
  const float* W1s = (const float*)d_in[7];
  const float* b1s = (const float*)d_in[8];
  const float* w2s = (const float*)d_in[9];
  const float* W1v = (const float*)d_in[10];
  const float* b1v = (const float*)d_in[11];
  const float* w2v = (const float*)d_in[12];
  const float* W1t = (const float*)d_in[13];
  const float* b1t = (const float*)d_in[14];
  const float* w2t = (const float*)d_in[15];
  const float* Wv  = (const float*)d_in[16];
  const float* bv  = (const float*)d_in[17];
  const float* Wt  = (const float*)d_in[18];
  const float* bt  = (const float*)d_in[19];
  const float* alphaP = (const float*)d_in[20];
  const float* gammaP = (const float*)d_in[21];
  float* outp = (float*)d_out;

  const int E   = in_sizes[2];
  const int N   = in_sizes[5] / DIM;
  const int NR  = in_sizes[6] / DIM;
  const int VIS = in_sizes[3] / N;   // 512
  const int TXT = in_sizes[4] / N;   // 768
  const int KMAX = (TXT > VIS) ? TXT : VIS;

  // ---- workspace layout (metadata first), gated on ws_size ----
  size_t off = 0;
  auto take = [&](size_t bytes) -> size_t {
    size_t o = off;
    off = (off + bytes + 255) & ~(size_t)255;
    return o;
  };
  size_t o_cnt  = take((size_t)2 * N * 4);
  size_t o_offs = take((size_t)(N + 1) * 4);
  size_t o_eid  = take((size_t)E * 4);
  size_t o_qd   = take((size_t)N * 4);
  size_t o_qs   = take((size_t)N * 4);
  size_t o_qr   = take((size_t)NR * 4);
  size_t o_Pr   = take((size_t)NR * 128 * 2);
  size_t o_Wc   = take((size_t)256 * KMAX * 2);   // combined bf16 B [256][K]
  size_t o_Pd   = take((size_t)N * 128 * 2);
  size_t o_Ps   = take((size_t)N * 128 * 2);
  size_t need   = off;   // ~6.9 MB (< round-5 proven 7.44 MB)

  if (ws_size < need) {
    hipMemsetAsync(d_out, 0, (size_t)out_size * 4, stream);  // finite diagnostic
    return;
  }

  char* w = (char*)d_ws;
  int* counts = (int*)(w + o_cnt);
  int* cursor = counts + N;
  int* offs   = (int*)(w + o_offs);
  int* eid    = (int*)(w + o_eid);
  float* qd   = (float*)(w + o_qd);
  float* qs   = (float*)(w + o_qs);
  float* qr   = (float*)(w + o_qr);
  u16* Pr     = (u16*)(w + o_Pr);
  u16* Wc     = (u16*)(w + o_Wc);
  u16* Pd     = (u16*)(w + o_Pd);
  u16* Ps     = (u16*)(w + o_Ps);

  const int* esrc = ei;
  const int* edst = ei + E;

  hipMemsetAsync(counts, 0, (size_t)2 * N * 4, stream);
  hipMemsetAsync(eid, 0, (size_t)E * 4, stream);

  int egrid = (E + 255) / 256;
  hist_k<<<egrid, 256, 0, stream>>>(edst, counts, E, N);
  scan_k<<<1, 1024, 0, stream>>>(counts, offs, N);
  scatter_k<<<egrid, 256, 0, stream>>>(edst, offs, cursor, eid, E, N);

  int gemmGrid = (N + 63) / 64;

  for (int m = 0; m < 3; ++m) {
    const float *W1, *b1, *w2, *Amod, *Wmod, *bmod;
    int K;
    if (m == 0)      { W1 = W1s; b1 = b1s; w2 = w2s; Amod = semb;    Wmod = nullptr; bmod = nullptr; K = DIM; }
    else if (m == 1) { W1 = W1v; b1 = b1v; w2 = w2v; Amod = visual;  Wmod = Wv;      bmod = bv;      K = VIS; }
    else             { W1 = W1t; b1 = b1t; w2 = w2t; Amod = textual; Wmod = Wt;      bmod = bt;      K = TXT; }

    if (m == 0) {
      copy_w1b<<<256, 128, 0, stream>>>(W1, Wc);
    } else {
      prep_wc2<<<dim3((K + 255) / 256, 256), 256, 0, stream>>>(W1, Wmod, K, Wc);
    }
    prep_pr_q<<<NR, 128, 0, stream>>>(relemb, W1, b1, bmod, w2, Pr, qr, NR);

    gemm2_mfma<<<gemmGrid, 256, 0, stream>>>(Amod, Wc, w2, Pd, Ps, qd, qs, N, K);

    aggregate_m<<<(N + 3) / 4, 256, 0, stream>>>(eid, offs, esrc, et,
                                                 qd, qs, qr, Pd, Ps, Pr,
                                                 alphaP, gammaP, m, (m == 0) ? 1 : 0,
                                                 outp, N, NR, E);
  }
}